// Round 1
// baseline (573.544 us; speedup 1.0000x reference)
//
#include <hip/hip_runtime.h>
#include <stdint.h>

static constexpr int NN  = 50000;
static constexpr int EE  = 800000;
static constexpr int FIN = 256;
static constexpr int HID = 128;

typedef __attribute__((ext_vector_type(8))) short  short8;
typedef __attribute__((ext_vector_type(8))) __bf16 bf16x8;
typedef __attribute__((ext_vector_type(4))) float  f32x4;
typedef uint16_t u16;

__device__ __forceinline__ u16 f2bf(float f) {
  union { float f; uint32_t u; } v; v.f = f;
  return (u16)((v.u + 0x7fffu + ((v.u >> 16) & 1u)) >> 16);  // RNE
}
__device__ __forceinline__ float bf2f(u16 b) {
  union { uint32_t u; float f; } v; v.u = ((uint32_t)b) << 16;
  return v.f;
}

// ---------------- CSR build ----------------
__global__ void k_zero(int* p, int n) {
  int i = blockIdx.x * 256 + threadIdx.x;
  if (i < n) p[i] = 0;
}

__global__ void k_count(const int* __restrict__ dst, int* __restrict__ cnt, int e) {
  int i = blockIdx.x * 256 + threadIdx.x;
  if (i < e) atomicAdd(&cnt[dst[i]], 1);
}

// single-block scan over N (50 chunks of 1024); also writes dinv and cur.
__global__ __launch_bounds__(1024) void k_scan(const int* __restrict__ cnt, int* __restrict__ off,
                                               int* __restrict__ cur, float* __restrict__ dinv, int n) {
  __shared__ int buf[1024];
  __shared__ int carry_s;
  int tid = threadIdx.x;
  if (tid == 0) carry_s = 0;
  __syncthreads();
  for (int base = 0; base < n; base += 1024) {
    int i = base + tid;
    int v = (i < n) ? cnt[i] : 0;
    buf[tid] = v;
    __syncthreads();
    for (int ofs = 1; ofs < 1024; ofs <<= 1) {
      int t = (tid >= ofs) ? buf[tid - ofs] : 0;
      __syncthreads();
      buf[tid] += t;
      __syncthreads();
    }
    int incl = buf[tid];
    int carry = carry_s;
    if (i < n) {
      int ex = carry + incl - v;
      off[i] = ex;
      cur[i] = ex;
      dinv[i] = rsqrtf((float)v + 2.0f);  // improved=True: +2.0 self-loop weight
    }
    __syncthreads();
    if (tid == 1023) carry_s = carry + incl;
    __syncthreads();
  }
  if (tid == 0) off[n] = carry_s;
}

__global__ void k_fill(const int* __restrict__ src, const int* __restrict__ dst, int* __restrict__ cur,
                       const float* __restrict__ dinv, int* __restrict__ psrc, float* __restrict__ pnorm, int e) {
  int i = blockIdx.x * 256 + threadIdx.x;
  if (i < e) {
    int s = src[i], d = dst[i];
    int pos = atomicAdd(&cur[d], 1);
    psrc[pos]  = s;
    pnorm[pos] = dinv[s] * dinv[d];
  }
}

// ---------------- weight convert: [K][128] f32 -> tiled bf16 [K/32][128][32] (B^T per K-block) ----
__global__ void k_wconv(const float* __restrict__ W, u16* __restrict__ out, int K) {
  int i = blockIdx.x * 256 + threadIdx.x;
  if (i < K * 128) {
    int k = i >> 7, c = i & 127;
    out[(size_t)((k >> 5) * 128 + c) * 32 + (k & 31)] = f2bf(W[i]);
  }
}

// ---------------- GEMM: [M,K] @ [K,128] -> [M,128], bf16 MFMA, f32 acc ----------------
// AFLOAT=1: A is f32 (converted on the fly). EPI=0: store bf16. EPI=1: bias+sigmoid, store f32.
template<int AFLOAT, int EPI>
__global__ __launch_bounds__(256) void k_gemm(const float* __restrict__ Af, const u16* __restrict__ Ah,
                                              const u16* __restrict__ Wt, const float* __restrict__ bias,
                                              u16* __restrict__ gout, float* __restrict__ fout,
                                              int M, int K) {
  __shared__ u16 Ash[64 * 40];    // 64 rows x 32 k, stride 40 (80B = 5*16B, conflict-free-ish)
  __shared__ u16 Bsh[128 * 40];   // 128 cols x 32 k (transposed)
  const int tid  = threadIdx.x;
  const int lane = tid & 63;
  const int w    = tid >> 6;
  const int row0 = blockIdx.x * 64;
  f32x4 acc[8];
#pragma unroll
  for (int t = 0; t < 8; ++t) acc[t] = (f32x4){0.f, 0.f, 0.f, 0.f};

  const int nk = K >> 5;
  const int r = tid >> 2, kg = tid & 3;
  const int grow_a = row0 + r;
  for (int kb = 0; kb < nk; ++kb) {
    // stage A tile (64x32)
    {
      int k0 = kb * 32 + kg * 8;
      alignas(16) u16 v[8];
      if (grow_a < M) {
        if (AFLOAT) {
          const float* p = Af + (size_t)grow_a * K + k0;
          float4 x0 = *(const float4*)(p);
          float4 x1 = *(const float4*)(p + 4);
          v[0] = f2bf(x0.x); v[1] = f2bf(x0.y); v[2] = f2bf(x0.z); v[3] = f2bf(x0.w);
          v[4] = f2bf(x1.x); v[5] = f2bf(x1.y); v[6] = f2bf(x1.z); v[7] = f2bf(x1.w);
        } else {
          *(uint4*)v = *(const uint4*)(Ah + (size_t)grow_a * K + k0);
        }
      } else {
#pragma unroll
        for (int i = 0; i < 8; ++i) v[i] = 0;
      }
      *(uint4*)&Ash[r * 40 + kg * 8] = *(const uint4*)v;
    }
    // stage B tile (32k x 128c) from tiled source, already transposed
    {
      const u16* wsrc = Wt + (size_t)kb * 4096;
#pragma unroll
      for (int j = 0; j < 2; ++j) {
        int chunk = tid * 2 + j;              // 0..511, 8 bf16 each
        int rowb = chunk >> 2, kk = (chunk & 3) << 3;
        *(uint4*)&Bsh[rowb * 40 + kk] = *(const uint4*)(wsrc + chunk * 8);
      }
    }
    __syncthreads();
    {
      const int rl = lane & 15, kq = lane >> 4;
      short8 af = *(const short8*)&Ash[(w * 16 + rl) * 40 + kq * 8];
#pragma unroll
      for (int t = 0; t < 8; ++t) {
        short8 bf = *(const short8*)&Bsh[(t * 16 + rl) * 40 + kq * 8];
        acc[t] = __builtin_amdgcn_mfma_f32_16x16x32_bf16(
            __builtin_bit_cast(bf16x8, af), __builtin_bit_cast(bf16x8, bf), acc[t], 0, 0, 0);
      }
    }
    __syncthreads();
  }
  // epilogue: C/D layout col=lane&15, row=(lane>>4)*4+i (m89-verified)
  const int rl = lane & 15, rq = lane >> 4;
#pragma unroll
  for (int t = 0; t < 8; ++t) {
    int col = t * 16 + rl;
#pragma unroll
    for (int i = 0; i < 4; ++i) {
      int grow = row0 + w * 16 + rq * 4 + i;
      if (grow < M) {
        if (EPI == 0) {
          gout[(size_t)grow * HID + col] = f2bf(acc[t][i]);
        } else {
          float vv = acc[t][i] + bias[col];
          fout[(size_t)grow * HID + col] = 1.0f / (1.0f + __expf(-vv));
        }
      }
    }
  }
}

// ---------------- aggregation: one wave per dst node, CSR gather, no atomics ----------------
// out[d] = bias + 2*dinv[d]^2 * h[d] + sum_e dinv[s]*dinv[d]*h[s];  optional ReLU; bf16 in/out.
template<int RELU>
__global__ __launch_bounds__(256) void k_agg(const u16* __restrict__ h, u16* __restrict__ g,
                                             const float* __restrict__ bias, const float* __restrict__ dinv,
                                             const int* __restrict__ off, const int* __restrict__ psrc,
                                             const float* __restrict__ pnorm, int n) {
  int wave = blockIdx.x * 4 + (threadIdx.x >> 6);
  int lane = threadIdx.x & 63;
  if (wave >= n) return;
  int d = wave;
  int c = lane << 1;
  float di = dinv[d];
  float sl = 2.0f * di * di;
  uint32_t self = *(const uint32_t*)(h + (size_t)d * HID + c);
  float a0 = bias[c]     + sl * bf2f((u16)(self & 0xffff));
  float a1 = bias[c + 1] + sl * bf2f((u16)(self >> 16));
  int j0 = off[d], j1 = off[d + 1];
  for (int j = j0; j < j1; ++j) {
    int s = psrc[j];
    float wn = pnorm[j];
    uint32_t v = *(const uint32_t*)(h + (size_t)s * HID + c);
    a0 += wn * bf2f((u16)(v & 0xffff));
    a1 += wn * bf2f((u16)(v >> 16));
  }
  if (RELU) { a0 = fmaxf(a0, 0.f); a1 = fmaxf(a1, 0.f); }
  *(uint32_t*)(g + (size_t)d * HID + c) = (uint32_t)f2bf(a0) | ((uint32_t)f2bf(a1) << 16);
}

extern "C" void kernel_launch(void* const* d_in, const int* in_sizes, int n_in,
                              void* d_out, int out_size, void* d_ws, size_t ws_size,
                              hipStream_t stream) {
  const float* x   = (const float*)d_in[0];
  const int*   ei  = (const int*)d_in[1];        // [2, E] int32
  const float* W1  = (const float*)d_in[2];
  const float* b1  = (const float*)d_in[3];
  const float* W2  = (const float*)d_in[4];
  const float* b2  = (const float*)d_in[5];
  const float* We  = (const float*)d_in[6];
  const float* be  = (const float*)d_in[7];
  const float* Wf  = (const float*)d_in[8];
  const float* bfv = (const float*)d_in[9];
  float* out = (float*)d_out;

  const int* src = ei;
  const int* dst = ei + EE;

  char* p = (char*)d_ws;
  auto take = [&](size_t bytes) { char* r = p; p += (bytes + 255) & ~(size_t)255; return r; };
  int*   cnt   = (int*)take((size_t)NN * 4);
  int*   off   = (int*)take((size_t)(NN + 1) * 4);
  int*   cur   = (int*)take((size_t)NN * 4);
  float* dinv  = (float*)take((size_t)NN * 4);
  int*   psrc  = (int*)take((size_t)EE * 4);
  float* pnorm = (float*)take((size_t)EE * 4);
  u16*   hA    = (u16*)take((size_t)NN * HID * 2);
  u16*   hB    = (u16*)take((size_t)NN * HID * 2);
  u16*   Wt1   = (u16*)take((size_t)FIN * HID * 2);
  u16*   Wt2   = (u16*)take((size_t)HID * HID * 2);
  u16*   Wt3   = (u16*)take((size_t)HID * HID * 2);
  u16*   Wt4   = (u16*)take((size_t)HID * HID * 2);

  // CSR build + norm
  k_zero<<<(NN + 255) / 256, 256, 0, stream>>>(cnt, NN);
  k_count<<<(EE + 255) / 256, 256, 0, stream>>>(dst, cnt, EE);
  k_scan<<<1, 1024, 0, stream>>>(cnt, off, cur, dinv, NN);
  k_fill<<<(EE + 255) / 256, 256, 0, stream>>>(src, dst, cur, dinv, psrc, pnorm, EE);

  // weights -> tiled bf16
  k_wconv<<<(FIN * HID + 255) / 256, 256, 0, stream>>>(W1, Wt1, FIN);
  k_wconv<<<(HID * HID + 255) / 256, 256, 0, stream>>>(W2, Wt2, HID);
  k_wconv<<<(HID * HID + 255) / 256, 256, 0, stream>>>(We, Wt3, HID);
  k_wconv<<<(HID * HID + 255) / 256, 256, 0, stream>>>(Wf, Wt4, HID);

  const int gemm_grid = (NN + 63) / 64;
  const int agg_grid  = (NN + 3) / 4;

  // layer 1: h = x@W1 ; g = relu(Agg(h) + b1)
  k_gemm<1, 0><<<gemm_grid, 256, 0, stream>>>(x, nullptr, Wt1, nullptr, hA, nullptr, NN, FIN);
  k_agg<1><<<agg_grid, 256, 0, stream>>>(hA, hB, b1, dinv, off, psrc, pnorm, NN);
  // layer 2
  k_gemm<0, 0><<<gemm_grid, 256, 0, stream>>>(nullptr, hB, Wt2, nullptr, hA, nullptr, NN, HID);
  k_agg<1><<<agg_grid, 256, 0, stream>>>(hA, hB, b2, dinv, off, psrc, pnorm, NN);
  // layer 3 (no relu)
  k_gemm<0, 0><<<gemm_grid, 256, 0, stream>>>(nullptr, hB, Wt3, nullptr, hA, nullptr, NN, HID);
  k_agg<0><<<agg_grid, 256, 0, stream>>>(hA, hB, be, dinv, off, psrc, pnorm, NN);
  // final dense + sigmoid
  k_gemm<0, 1><<<gemm_grid, 256, 0, stream>>>(nullptr, hB, Wt4, bfv, nullptr, out, NN, HID);
}

// Round 2
// 397.509 us; speedup vs baseline: 1.4428x; 1.4428x over previous
//
#include <hip/hip_runtime.h>
#include <stdint.h>

static constexpr int NN  = 50000;
static constexpr int EE  = 800000;
static constexpr int FIN = 256;
static constexpr int HID = 128;
static constexpr int SCAN_NB = (NN + 1023) / 1024;   // 49

typedef __attribute__((ext_vector_type(8))) short  short8;
typedef __attribute__((ext_vector_type(8))) __bf16 bf16x8;
typedef __attribute__((ext_vector_type(4))) float  f32x4;
typedef uint16_t u16;

__device__ __forceinline__ u16 f2bf(float f) {
  union { float f; uint32_t u; } v; v.f = f;
  return (u16)((v.u + 0x7fffu + ((v.u >> 16) & 1u)) >> 16);  // RNE
}
__device__ __forceinline__ float bf2f(u16 b) {
  union { uint32_t u; float f; } v; v.u = ((uint32_t)b) << 16;
  return v.f;
}

// ---------------- CSR build ----------------
__global__ void k_zero(int* p, int n) {
  int i = blockIdx.x * 256 + threadIdx.x;
  if (i < n) p[i] = 0;
}

__global__ void k_count(const int* __restrict__ dst, int* __restrict__ cnt, int e) {
  int i = blockIdx.x * 256 + threadIdx.x;
  if (i < e) atomicAdd(&cnt[dst[i]], 1);
}

// hierarchical scan, stage 1: per-block inclusive scan + block sums
__global__ __launch_bounds__(1024) void k_scan1(const int* __restrict__ cnt, int* __restrict__ incl,
                                                int* __restrict__ bsum, int n) {
  __shared__ int buf[1024];
  int tid = threadIdx.x;
  int i = blockIdx.x * 1024 + tid;
  int v = (i < n) ? cnt[i] : 0;
  buf[tid] = v;
  __syncthreads();
  for (int ofs = 1; ofs < 1024; ofs <<= 1) {
    int t = (tid >= ofs) ? buf[tid - ofs] : 0;
    __syncthreads();
    buf[tid] += t;
    __syncthreads();
  }
  if (i < n) incl[i] = buf[tid];
  if (tid == 1023) bsum[blockIdx.x] = buf[tid];
}

// stage 2: block offset via in-wave reduce of preceding block sums (SCAN_NB<=64),
// then exclusive offsets + cur + dinv.
__global__ __launch_bounds__(1024) void k_scan3(const int* __restrict__ cnt, const int* __restrict__ incl,
                                                const int* __restrict__ bsum, int* __restrict__ off,
                                                int* __restrict__ cur, float* __restrict__ dinv, int n) {
  __shared__ int boff_s;
  int tid = threadIdx.x;
  if (tid < 64) {
    int v = (tid < (int)blockIdx.x) ? bsum[tid] : 0;
    for (int o = 32; o > 0; o >>= 1) v += __shfl_down(v, o);
    if (tid == 0) boff_s = v;
  }
  __syncthreads();
  int boff = boff_s;
  int i = blockIdx.x * 1024 + tid;
  if (i < n) {
    int v = cnt[i];
    int ex = boff + incl[i] - v;
    off[i] = ex;
    cur[i] = ex;
    dinv[i] = rsqrtf((float)v + 2.0f);  // improved=True: +2.0 self-loop weight
  }
  if (i == n - 1) off[n] = boff + incl[i];
}

__global__ void k_fill(const int* __restrict__ src, const int* __restrict__ dst, int* __restrict__ cur,
                       const float* __restrict__ dinv, int2* __restrict__ edges, int e) {
  int i = blockIdx.x * 256 + threadIdx.x;
  if (i < e) {
    int s = src[i], d = dst[i];
    int pos = atomicAdd(&cur[d], 1);
    edges[pos] = make_int2(s, __float_as_int(dinv[s] * dinv[d]));
  }
}

// ---------------- weight convert (all four), [K][128] f32 -> tiled bf16 [K/32][128][32] ----
__global__ void k_wconv_all(const float* __restrict__ W1, const float* __restrict__ W2,
                            const float* __restrict__ We, const float* __restrict__ Wf,
                            u16* __restrict__ T1, u16* __restrict__ T2,
                            u16* __restrict__ T3, u16* __restrict__ T4) {
  int i = blockIdx.x * 256 + threadIdx.x;   // 0 .. 81920
  const float* W; u16* o;
  if (i < 32768)      { W = W1; o = T1; }
  else if (i < 49152) { W = W2; o = T2; i -= 32768; }
  else if (i < 65536) { W = We; o = T3; i -= 49152; }
  else                { W = Wf; o = T4; i -= 65536; }
  int k = i >> 7, c = i & 127;
  o[(size_t)((k >> 5) * 128 + c) * 32 + (k & 31)] = f2bf(W[i]);
}

// ---------------- GEMM: [M,K] @ [K,128] -> [M,128], bf16 MFMA, f32 acc ----------------
template<int AFLOAT, int EPI>
__global__ __launch_bounds__(256) void k_gemm(const float* __restrict__ Af, const u16* __restrict__ Ah,
                                              const u16* __restrict__ Wt, const float* __restrict__ bias,
                                              u16* __restrict__ gout, float* __restrict__ fout,
                                              int M, int K) {
  __shared__ u16 Ash[64 * 40];
  __shared__ u16 Bsh[128 * 40];
  const int tid  = threadIdx.x;
  const int lane = tid & 63;
  const int w    = tid >> 6;
  const int row0 = blockIdx.x * 64;
  f32x4 acc[8];
#pragma unroll
  for (int t = 0; t < 8; ++t) acc[t] = (f32x4){0.f, 0.f, 0.f, 0.f};

  const int nk = K >> 5;
  const int r = tid >> 2, kg = tid & 3;
  const int grow_a = row0 + r;
  for (int kb = 0; kb < nk; ++kb) {
    {
      int k0 = kb * 32 + kg * 8;
      alignas(16) u16 v[8];
      if (grow_a < M) {
        if (AFLOAT) {
          const float* p = Af + (size_t)grow_a * K + k0;
          float4 x0 = *(const float4*)(p);
          float4 x1 = *(const float4*)(p + 4);
          v[0] = f2bf(x0.x); v[1] = f2bf(x0.y); v[2] = f2bf(x0.z); v[3] = f2bf(x0.w);
          v[4] = f2bf(x1.x); v[5] = f2bf(x1.y); v[6] = f2bf(x1.z); v[7] = f2bf(x1.w);
        } else {
          *(uint4*)v = *(const uint4*)(Ah + (size_t)grow_a * K + k0);
        }
      } else {
#pragma unroll
        for (int i = 0; i < 8; ++i) v[i] = 0;
      }
      *(uint4*)&Ash[r * 40 + kg * 8] = *(const uint4*)v;
    }
    {
      const u16* wsrc = Wt + (size_t)kb * 4096;
#pragma unroll
      for (int j = 0; j < 2; ++j) {
        int chunk = tid * 2 + j;
        int rowb = chunk >> 2, kk = (chunk & 3) << 3;
        *(uint4*)&Bsh[rowb * 40 + kk] = *(const uint4*)(wsrc + chunk * 8);
      }
    }
    __syncthreads();
    {
      const int rl = lane & 15, kq = lane >> 4;
      short8 af = *(const short8*)&Ash[(w * 16 + rl) * 40 + kq * 8];
#pragma unroll
      for (int t = 0; t < 8; ++t) {
        short8 bf = *(const short8*)&Bsh[(t * 16 + rl) * 40 + kq * 8];
        acc[t] = __builtin_amdgcn_mfma_f32_16x16x32_bf16(
            __builtin_bit_cast(bf16x8, af), __builtin_bit_cast(bf16x8, bf), acc[t], 0, 0, 0);
      }
    }
    __syncthreads();
  }
  const int rl = lane & 15, rq = lane >> 4;
#pragma unroll
  for (int t = 0; t < 8; ++t) {
    int col = t * 16 + rl;
#pragma unroll
    for (int i = 0; i < 4; ++i) {
      int grow = row0 + w * 16 + rq * 4 + i;
      if (grow < M) {
        if (EPI == 0) {
          gout[(size_t)grow * HID + col] = f2bf(acc[t][i]);
        } else {
          float vv = acc[t][i] + bias[col];
          fout[(size_t)grow * HID + col] = 1.0f / (1.0f + __expf(-vv));
        }
      }
    }
  }
}

// ---------------- aggregation: one wave per dst node, CSR gather, no atomics ----------------
template<int RELU>
__global__ __launch_bounds__(256) void k_agg(const u16* __restrict__ h, u16* __restrict__ g,
                                             const float* __restrict__ bias, const float* __restrict__ dinv,
                                             const int* __restrict__ off, const int2* __restrict__ edges,
                                             int n) {
  int wave = blockIdx.x * 4 + (threadIdx.x >> 6);
  int lane = threadIdx.x & 63;
  if (wave >= n) return;
  int d = wave;
  int c = lane << 1;
  float di = dinv[d];
  float sl = 2.0f * di * di;
  uint32_t self = *(const uint32_t*)(h + (size_t)d * HID + c);
  float a0 = bias[c]     + sl * bf2f((u16)(self & 0xffff));
  float a1 = bias[c + 1] + sl * bf2f((u16)(self >> 16));
  int j = off[d], j1 = off[d + 1];
  // unrolled x2: two independent gathers in flight
  for (; j + 1 < j1; j += 2) {
    int2 eA = edges[j], eB = edges[j + 1];
    uint32_t vA = *(const uint32_t*)(h + (size_t)eA.x * HID + c);
    uint32_t vB = *(const uint32_t*)(h + (size_t)eB.x * HID + c);
    float wA = __int_as_float(eA.y), wB = __int_as_float(eB.y);
    a0 += wA * bf2f((u16)(vA & 0xffff));
    a1 += wA * bf2f((u16)(vA >> 16));
    a0 += wB * bf2f((u16)(vB & 0xffff));
    a1 += wB * bf2f((u16)(vB >> 16));
  }
  if (j < j1) {
    int2 eA = edges[j];
    uint32_t vA = *(const uint32_t*)(h + (size_t)eA.x * HID + c);
    float wA = __int_as_float(eA.y);
    a0 += wA * bf2f((u16)(vA & 0xffff));
    a1 += wA * bf2f((u16)(vA >> 16));
  }
  if (RELU) { a0 = fmaxf(a0, 0.f); a1 = fmaxf(a1, 0.f); }
  *(uint32_t*)(g + (size_t)d * HID + c) = (uint32_t)f2bf(a0) | ((uint32_t)f2bf(a1) << 16);
}

extern "C" void kernel_launch(void* const* d_in, const int* in_sizes, int n_in,
                              void* d_out, int out_size, void* d_ws, size_t ws_size,
                              hipStream_t stream) {
  const float* x   = (const float*)d_in[0];
  const int*   ei  = (const int*)d_in[1];        // [2, E] int32
  const float* W1  = (const float*)d_in[2];
  const float* b1  = (const float*)d_in[3];
  const float* W2  = (const float*)d_in[4];
  const float* b2  = (const float*)d_in[5];
  const float* We  = (const float*)d_in[6];
  const float* be  = (const float*)d_in[7];
  const float* Wf  = (const float*)d_in[8];
  const float* bfv = (const float*)d_in[9];
  float* out = (float*)d_out;

  const int* src = ei;
  const int* dst = ei + EE;

  char* p = (char*)d_ws;
  auto take = [&](size_t bytes) { char* r = p; p += (bytes + 255) & ~(size_t)255; return r; };
  int*   cnt   = (int*)take((size_t)NN * 4);
  int*   incl  = (int*)take((size_t)NN * 4);
  int*   bsum  = (int*)take((size_t)SCAN_NB * 4);
  int*   off   = (int*)take((size_t)(NN + 1) * 4);
  int*   cur   = (int*)take((size_t)NN * 4);
  float* dinv  = (float*)take((size_t)NN * 4);
  int2*  edges = (int2*)take((size_t)EE * 8);
  u16*   hA    = (u16*)take((size_t)NN * HID * 2);
  u16*   hB    = (u16*)take((size_t)NN * HID * 2);
  u16*   Wt1   = (u16*)take((size_t)FIN * HID * 2);
  u16*   Wt2   = (u16*)take((size_t)HID * HID * 2);
  u16*   Wt3   = (u16*)take((size_t)HID * HID * 2);
  u16*   Wt4   = (u16*)take((size_t)HID * HID * 2);

  // CSR build + norm
  k_zero<<<(NN + 255) / 256, 256, 0, stream>>>(cnt, NN);
  k_count<<<(EE + 255) / 256, 256, 0, stream>>>(dst, cnt, EE);
  k_scan1<<<SCAN_NB, 1024, 0, stream>>>(cnt, incl, bsum, NN);
  k_scan3<<<SCAN_NB, 1024, 0, stream>>>(cnt, incl, bsum, off, cur, dinv, NN);
  k_fill<<<(EE + 255) / 256, 256, 0, stream>>>(src, dst, cur, dinv, edges, EE);

  // weights -> tiled bf16 (single launch)
  k_wconv_all<<<(81920 + 255) / 256, 256, 0, stream>>>(W1, W2, We, Wf, Wt1, Wt2, Wt3, Wt4);

  const int gemm_grid = (NN + 63) / 64;
  const int agg_grid  = (NN + 3) / 4;

  // layer 1: h = x@W1 ; g = relu(Agg(h) + b1)
  k_gemm<1, 0><<<gemm_grid, 256, 0, stream>>>(x, nullptr, Wt1, nullptr, hA, nullptr, NN, FIN);
  k_agg<1><<<agg_grid, 256, 0, stream>>>(hA, hB, b1, dinv, off, edges, NN);
  // layer 2
  k_gemm<0, 0><<<gemm_grid, 256, 0, stream>>>(nullptr, hB, Wt2, nullptr, hA, nullptr, NN, HID);
  k_agg<1><<<agg_grid, 256, 0, stream>>>(hA, hB, b2, dinv, off, edges, NN);
  // layer 3 (no relu)
  k_gemm<0, 0><<<gemm_grid, 256, 0, stream>>>(nullptr, hB, Wt3, nullptr, hA, nullptr, NN, HID);
  k_agg<0><<<agg_grid, 256, 0, stream>>>(hA, hB, be, dinv, off, edges, NN);
  // final dense + sigmoid
  k_gemm<0, 1><<<gemm_grid, 256, 0, stream>>>(nullptr, hB, Wt4, bfv, nullptr, out, NN, HID);
}

// Round 3
// 346.462 us; speedup vs baseline: 1.6554x; 1.1473x over previous
//
#include <hip/hip_runtime.h>
#include <stdint.h>

static constexpr int NN  = 50000;
static constexpr int EE  = 800000;
static constexpr int FIN = 256;
static constexpr int HID = 128;
static constexpr int SCAN_NB = (NN + 1023) / 1024;   // 49

typedef __attribute__((ext_vector_type(8))) short  short8;
typedef __attribute__((ext_vector_type(8))) __bf16 bf16x8;
typedef __attribute__((ext_vector_type(4))) float  f32x4;
typedef uint16_t u16;

__device__ __forceinline__ u16 f2bf(float f) {
  union { float f; uint32_t u; } v; v.f = f;
  return (u16)((v.u + 0x7fffu + ((v.u >> 16) & 1u)) >> 16);  // RNE
}
__device__ __forceinline__ float bf2f(u16 b) {
  union { uint32_t u; float f; } v; v.u = ((uint32_t)b) << 16;
  return v.f;
}
__device__ __forceinline__ float bflo(uint32_t u) {   // low bf16 of packed pair
  union { uint32_t u; float f; } v; v.u = u << 16; return v.f;
}
__device__ __forceinline__ float bfhi(uint32_t u) {   // high bf16 of packed pair
  union { uint32_t u; float f; } v; v.u = u & 0xffff0000u; return v.f;
}

// ---------------- CSR build ----------------
__global__ void k_zero(int* p, int n) {
  int i = blockIdx.x * 256 + threadIdx.x;
  if (i < n) p[i] = 0;
}

__global__ void k_count(const int* __restrict__ dst, int* __restrict__ cnt, int e) {
  int i = blockIdx.x * 256 + threadIdx.x;
  if (i < e) atomicAdd(&cnt[dst[i]], 1);
}

// hierarchical scan, stage 1: per-block inclusive scan + block sums
__global__ __launch_bounds__(1024) void k_scan1(const int* __restrict__ cnt, int* __restrict__ incl,
                                                int* __restrict__ bsum, int n) {
  __shared__ int buf[1024];
  int tid = threadIdx.x;
  int i = blockIdx.x * 1024 + tid;
  int v = (i < n) ? cnt[i] : 0;
  buf[tid] = v;
  __syncthreads();
  for (int ofs = 1; ofs < 1024; ofs <<= 1) {
    int t = (tid >= ofs) ? buf[tid - ofs] : 0;
    __syncthreads();
    buf[tid] += t;
    __syncthreads();
  }
  if (i < n) incl[i] = buf[tid];
  if (tid == 1023) bsum[blockIdx.x] = buf[tid];
}

// stage 2: block offset via in-wave reduce of preceding block sums (SCAN_NB<=64)
__global__ __launch_bounds__(1024) void k_scan3(const int* __restrict__ cnt, const int* __restrict__ incl,
                                                const int* __restrict__ bsum, int* __restrict__ off,
                                                int* __restrict__ cur, float* __restrict__ dinv, int n) {
  __shared__ int boff_s;
  int tid = threadIdx.x;
  if (tid < 64) {
    int v = (tid < (int)blockIdx.x) ? bsum[tid] : 0;
    for (int o = 32; o > 0; o >>= 1) v += __shfl_down(v, o);
    if (tid == 0) boff_s = v;
  }
  __syncthreads();
  int boff = boff_s;
  int i = blockIdx.x * 1024 + tid;
  if (i < n) {
    int v = cnt[i];
    int ex = boff + incl[i] - v;
    off[i] = ex;
    cur[i] = ex;
    dinv[i] = rsqrtf((float)v + 2.0f);  // improved=True: +2.0 self-loop weight
  }
  if (i == n - 1) off[n] = boff + incl[i];
}

__global__ void k_fill(const int* __restrict__ src, const int* __restrict__ dst, int* __restrict__ cur,
                       const float* __restrict__ dinv, int2* __restrict__ edges, int e) {
  int i = blockIdx.x * 256 + threadIdx.x;
  if (i < e) {
    int s = src[i], d = dst[i];
    int pos = atomicAdd(&cur[d], 1);
    edges[pos] = make_int2(s, __float_as_int(dinv[s] * dinv[d]));
  }
}

// ---------------- weight convert (all four), [K][128] f32 -> tiled bf16 [K/32][128][32] ----
__global__ void k_wconv_all(const float* __restrict__ W1, const float* __restrict__ W2,
                            const float* __restrict__ We, const float* __restrict__ Wf,
                            u16* __restrict__ T1, u16* __restrict__ T2,
                            u16* __restrict__ T3, u16* __restrict__ T4) {
  int i = blockIdx.x * 256 + threadIdx.x;   // 0 .. 81920
  const float* W; u16* o;
  if (i < 32768)      { W = W1; o = T1; }
  else if (i < 49152) { W = W2; o = T2; i -= 32768; }
  else if (i < 65536) { W = We; o = T3; i -= 49152; }
  else                { W = Wf; o = T4; i -= 65536; }
  int k = i >> 7, c = i & 127;
  o[(size_t)((k >> 5) * 128 + c) * 32 + (k & 31)] = f2bf(W[i]);
}

// ---------------- GEMM: [M,K] @ [K,128] -> [M,128], bf16 MFMA, f32 acc ----------------
template<int AFLOAT, int EPI>
__global__ __launch_bounds__(256) void k_gemm(const float* __restrict__ Af, const u16* __restrict__ Ah,
                                              const u16* __restrict__ Wt, const float* __restrict__ bias,
                                              u16* __restrict__ gout, float* __restrict__ fout,
                                              int M, int K) {
  __shared__ u16 Ash[64 * 40];
  __shared__ u16 Bsh[128 * 40];
  const int tid  = threadIdx.x;
  const int lane = tid & 63;
  const int w    = tid >> 6;
  const int row0 = blockIdx.x * 64;
  f32x4 acc[8];
#pragma unroll
  for (int t = 0; t < 8; ++t) acc[t] = (f32x4){0.f, 0.f, 0.f, 0.f};

  const int nk = K >> 5;
  const int r = tid >> 2, kg = tid & 3;
  const int grow_a = row0 + r;
  for (int kb = 0; kb < nk; ++kb) {
    {
      int k0 = kb * 32 + kg * 8;
      alignas(16) u16 v[8];
      if (grow_a < M) {
        if (AFLOAT) {
          const float* p = Af + (size_t)grow_a * K + k0;
          float4 x0 = *(const float4*)(p);
          float4 x1 = *(const float4*)(p + 4);
          v[0] = f2bf(x0.x); v[1] = f2bf(x0.y); v[2] = f2bf(x0.z); v[3] = f2bf(x0.w);
          v[4] = f2bf(x1.x); v[5] = f2bf(x1.y); v[6] = f2bf(x1.z); v[7] = f2bf(x1.w);
        } else {
          *(uint4*)v = *(const uint4*)(Ah + (size_t)grow_a * K + k0);
        }
      } else {
#pragma unroll
        for (int i = 0; i < 8; ++i) v[i] = 0;
      }
      *(uint4*)&Ash[r * 40 + kg * 8] = *(const uint4*)v;
    }
    {
      const u16* wsrc = Wt + (size_t)kb * 4096;
#pragma unroll
      for (int j = 0; j < 2; ++j) {
        int chunk = tid * 2 + j;
        int rowb = chunk >> 2, kk = (chunk & 3) << 3;
        *(uint4*)&Bsh[rowb * 40 + kk] = *(const uint4*)(wsrc + chunk * 8);
      }
    }
    __syncthreads();
    {
      const int rl = lane & 15, kq = lane >> 4;
      short8 af = *(const short8*)&Ash[(w * 16 + rl) * 40 + kq * 8];
#pragma unroll
      for (int t = 0; t < 8; ++t) {
        short8 bf = *(const short8*)&Bsh[(t * 16 + rl) * 40 + kq * 8];
        acc[t] = __builtin_amdgcn_mfma_f32_16x16x32_bf16(
            __builtin_bit_cast(bf16x8, af), __builtin_bit_cast(bf16x8, bf), acc[t], 0, 0, 0);
      }
    }
    __syncthreads();
  }
  const int rl = lane & 15, rq = lane >> 4;
#pragma unroll
  for (int t = 0; t < 8; ++t) {
    int col = t * 16 + rl;
#pragma unroll
    for (int i = 0; i < 4; ++i) {
      int grow = row0 + w * 16 + rq * 4 + i;
      if (grow < M) {
        if (EPI == 0) {
          gout[(size_t)grow * HID + col] = f2bf(acc[t][i]);
        } else {
          float vv = acc[t][i] + bias[col];
          fout[(size_t)grow * HID + col] = 1.0f / (1.0f + __expf(-vv));
        }
      }
    }
  }
}

// ---------------- aggregation: one wave per dst node, 4 edge-groups x 16 lanes ----------------
// lane = g*16+t; group g handles edges j0+g, j0+g+4, ... ; each lane covers cols t*8..t*8+7
// via uint4 (8 bf16). Unroll x2 -> 8 row-gathers in flight per wave. Butterfly-combine groups.
template<int RELU>
__global__ __launch_bounds__(256) void k_agg(const u16* __restrict__ h, u16* __restrict__ g,
                                             const float* __restrict__ bias, const float* __restrict__ dinv,
                                             const int* __restrict__ off, const int2* __restrict__ edges,
                                             int n) {
  int wave = blockIdx.x * 4 + (threadIdx.x >> 6);
  int lane = threadIdx.x & 63;
  if (wave >= n) return;
  const int d  = wave;
  const int gr = lane >> 4;          // group 0..3
  const int t  = lane & 15;
  const int c  = t << 3;             // 8 columns per lane
  float a[8];
#pragma unroll
  for (int i = 0; i < 8; ++i) a[i] = 0.f;

  int j  = off[d] + gr;
  const int j1 = off[d + 1];
  // unrolled x2 per group: 2 gathers in flight per group, 8 per wave
  for (; j + 4 < j1; j += 8) {
    int2 eA = edges[j], eB = edges[j + 4];
    uint4 vA = *(const uint4*)(h + (size_t)eA.x * HID + c);
    uint4 vB = *(const uint4*)(h + (size_t)eB.x * HID + c);
    float wA = __int_as_float(eA.y), wB = __int_as_float(eB.y);
    a[0] += wA * bflo(vA.x); a[1] += wA * bfhi(vA.x);
    a[2] += wA * bflo(vA.y); a[3] += wA * bfhi(vA.y);
    a[4] += wA * bflo(vA.z); a[5] += wA * bfhi(vA.z);
    a[6] += wA * bflo(vA.w); a[7] += wA * bfhi(vA.w);
    a[0] += wB * bflo(vB.x); a[1] += wB * bfhi(vB.x);
    a[2] += wB * bflo(vB.y); a[3] += wB * bfhi(vB.y);
    a[4] += wB * bflo(vB.z); a[5] += wB * bfhi(vB.z);
    a[6] += wB * bflo(vB.w); a[7] += wB * bfhi(vB.w);
  }
  for (; j < j1; j += 4) {
    int2 eA = edges[j];
    uint4 vA = *(const uint4*)(h + (size_t)eA.x * HID + c);
    float wA = __int_as_float(eA.y);
    a[0] += wA * bflo(vA.x); a[1] += wA * bfhi(vA.x);
    a[2] += wA * bflo(vA.y); a[3] += wA * bfhi(vA.y);
    a[4] += wA * bflo(vA.z); a[5] += wA * bfhi(vA.z);
    a[6] += wA * bflo(vA.w); a[7] += wA * bfhi(vA.w);
  }
  // combine the 4 groups: lanes (t, t+16, t+32, t+48) hold partials of the same cols
#pragma unroll
  for (int i = 0; i < 8; ++i) {
    a[i] += __shfl_xor(a[i], 16);
    a[i] += __shfl_xor(a[i], 32);
  }
  // self-loop + bias (+ReLU), then lanes of group 0 store 16B each
  float di = dinv[d];
  float sl = 2.0f * di * di;
  uint4 sv = *(const uint4*)(h + (size_t)d * HID + c);
  const float4 bv0 = *(const float4*)(bias + c);
  const float4 bv1 = *(const float4*)(bias + c + 4);
  a[0] += sl * bflo(sv.x) + bv0.x; a[1] += sl * bfhi(sv.x) + bv0.y;
  a[2] += sl * bflo(sv.y) + bv0.z; a[3] += sl * bfhi(sv.y) + bv0.w;
  a[4] += sl * bflo(sv.z) + bv1.x; a[5] += sl * bfhi(sv.z) + bv1.y;
  a[6] += sl * bflo(sv.w) + bv1.z; a[7] += sl * bfhi(sv.w) + bv1.w;
  if (RELU) {
#pragma unroll
    for (int i = 0; i < 8; ++i) a[i] = fmaxf(a[i], 0.f);
  }
  if (gr == 0) {
    uint4 o;
    o.x = (uint32_t)f2bf(a[0]) | ((uint32_t)f2bf(a[1]) << 16);
    o.y = (uint32_t)f2bf(a[2]) | ((uint32_t)f2bf(a[3]) << 16);
    o.z = (uint32_t)f2bf(a[4]) | ((uint32_t)f2bf(a[5]) << 16);
    o.w = (uint32_t)f2bf(a[6]) | ((uint32_t)f2bf(a[7]) << 16);
    *(uint4*)(g + (size_t)d * HID + c) = o;
  }
}

extern "C" void kernel_launch(void* const* d_in, const int* in_sizes, int n_in,
                              void* d_out, int out_size, void* d_ws, size_t ws_size,
                              hipStream_t stream) {
  const float* x   = (const float*)d_in[0];
  const int*   ei  = (const int*)d_in[1];        // [2, E] int32
  const float* W1  = (const float*)d_in[2];
  const float* b1  = (const float*)d_in[3];
  const float* W2  = (const float*)d_in[4];
  const float* b2  = (const float*)d_in[5];
  const float* We  = (const float*)d_in[6];
  const float* be  = (const float*)d_in[7];
  const float* Wf  = (const float*)d_in[8];
  const float* bfv = (const float*)d_in[9];
  float* out = (float*)d_out;

  const int* src = ei;
  const int* dst = ei + EE;

  char* p = (char*)d_ws;
  auto take = [&](size_t bytes) { char* r = p; p += (bytes + 255) & ~(size_t)255; return r; };
  int*   cnt   = (int*)take((size_t)NN * 4);
  int*   incl  = (int*)take((size_t)NN * 4);
  int*   bsum  = (int*)take((size_t)SCAN_NB * 4);
  int*   off   = (int*)take((size_t)(NN + 1) * 4);
  int*   cur   = (int*)take((size_t)NN * 4);
  float* dinv  = (float*)take((size_t)NN * 4);
  int2*  edges = (int2*)take((size_t)EE * 8);
  u16*   hA    = (u16*)take((size_t)NN * HID * 2);
  u16*   hB    = (u16*)take((size_t)NN * HID * 2);
  u16*   Wt1   = (u16*)take((size_t)FIN * HID * 2);
  u16*   Wt2   = (u16*)take((size_t)HID * HID * 2);
  u16*   Wt3   = (u16*)take((size_t)HID * HID * 2);
  u16*   Wt4   = (u16*)take((size_t)HID * HID * 2);

  // CSR build + norm
  k_zero<<<(NN + 255) / 256, 256, 0, stream>>>(cnt, NN);
  k_count<<<(EE + 255) / 256, 256, 0, stream>>>(dst, cnt, EE);
  k_scan1<<<SCAN_NB, 1024, 0, stream>>>(cnt, incl, bsum, NN);
  k_scan3<<<SCAN_NB, 1024, 0, stream>>>(cnt, incl, bsum, off, cur, dinv, NN);
  k_fill<<<(EE + 255) / 256, 256, 0, stream>>>(src, dst, cur, dinv, edges, EE);

  // weights -> tiled bf16 (single launch)
  k_wconv_all<<<(81920 + 255) / 256, 256, 0, stream>>>(W1, W2, We, Wf, Wt1, Wt2, Wt3, Wt4);

  const int gemm_grid = (NN + 63) / 64;
  const int agg_grid  = (NN + 3) / 4;

  // layer 1: h = x@W1 ; g = relu(Agg(h) + b1)
  k_gemm<1, 0><<<gemm_grid, 256, 0, stream>>>(x, nullptr, Wt1, nullptr, hA, nullptr, NN, FIN);
  k_agg<1><<<agg_grid, 256, 0, stream>>>(hA, hB, b1, dinv, off, edges, NN);
  // layer 2
  k_gemm<0, 0><<<gemm_grid, 256, 0, stream>>>(nullptr, hB, Wt2, nullptr, hA, nullptr, NN, HID);
  k_agg<1><<<agg_grid, 256, 0, stream>>>(hA, hB, b2, dinv, off, edges, NN);
  // layer 3 (no relu)
  k_gemm<0, 0><<<gemm_grid, 256, 0, stream>>>(nullptr, hB, Wt3, nullptr, hA, nullptr, NN, HID);
  k_agg<0><<<agg_grid, 256, 0, stream>>>(hA, hB, be, dinv, off, edges, NN);
  // final dense + sigmoid
  k_gemm<0, 1><<<gemm_grid, 256, 0, stream>>>(nullptr, hB, Wt4, bfv, nullptr, out, NN, HID);
}

// Round 4
// 303.982 us; speedup vs baseline: 1.8868x; 1.1397x over previous
//
#include <hip/hip_runtime.h>
#include <stdint.h>

static constexpr int NN  = 50000;
static constexpr int EE  = 800000;
static constexpr int FIN = 256;
static constexpr int HID = 128;
static constexpr int SZ_LOG = 8;                       // 256 nodes per bucket
static constexpr int NBUCK  = (NN + 255) >> SZ_LOG;    // 196
static constexpr int CH     = 2048;                    // edges per block (hist/scatter)
static constexpr int NCBLK  = (EE + CH - 1) / CH;      // 391

typedef __attribute__((ext_vector_type(8))) short  short8;
typedef __attribute__((ext_vector_type(8))) __bf16 bf16x8;
typedef __attribute__((ext_vector_type(4))) float  f32x4;
typedef uint16_t u16;

__device__ __forceinline__ u16 f2bf(float f) {
  union { float f; uint32_t u; } v; v.f = f;
  return (u16)((v.u + 0x7fffu + ((v.u >> 16) & 1u)) >> 16);  // RNE
}
__device__ __forceinline__ float bflo(uint32_t u) {
  union { uint32_t u; float f; } v; v.u = u << 16; return v.f;
}
__device__ __forceinline__ float bfhi(uint32_t u) {
  union { uint32_t u; float f; } v; v.u = u & 0xffff0000u; return v.f;
}

// ---------------- bucketed CSR build ----------------
__global__ void k_zero(int* p, int n) {
  int i = blockIdx.x * 256 + threadIdx.x;
  if (i < n) p[i] = 0;
}

// A: bucket histogram, LDS-aggregated
__global__ __launch_bounds__(256) void k_bhist(const int* __restrict__ dst, int* __restrict__ bcnt, int e) {
  __shared__ int lc[NBUCK];
  int tid = threadIdx.x;
  for (int i = tid; i < NBUCK; i += 256) lc[i] = 0;
  __syncthreads();
  int base = blockIdx.x * CH;
#pragma unroll
  for (int j = 0; j < 8; ++j) {
    int i = base + j * 256 + tid;
    if (i < e) atomicAdd(&lc[dst[i] >> SZ_LOG], 1);
  }
  __syncthreads();
  for (int i = tid; i < NBUCK; i += 256) if (lc[i]) atomicAdd(&bcnt[i], lc[i]);
}

// B: scan 196 bucket counts (1 block)
__global__ __launch_bounds__(256) void k_bscan(const int* __restrict__ bcnt, int* __restrict__ boff,
                                               int* __restrict__ bcur, int* __restrict__ off) {
  __shared__ int buf[256];
  int tid = threadIdx.x;
  int v = (tid < NBUCK) ? bcnt[tid] : 0;
  buf[tid] = v;
  __syncthreads();
  for (int o = 1; o < 256; o <<= 1) {
    int t = (tid >= o) ? buf[tid - o] : 0;
    __syncthreads();
    buf[tid] += t;
    __syncthreads();
  }
  int ex = buf[tid] - v;
  if (tid < NBUCK) { boff[tid] = ex; bcur[tid] = ex; }
  if (tid == NBUCK - 1) boff[NBUCK] = ex + v;   // == EE
  if (tid == 0) off[NN] = EE;
}

// C: scatter (s,d) into bucket-contiguous storage; per-block chunk reservation
__global__ __launch_bounds__(256) void k_bscatter(const int* __restrict__ src, const int* __restrict__ dst,
                                                  int* __restrict__ bcur, int2* __restrict__ ebuck, int e) {
  __shared__ int lc[NBUCK];
  __shared__ int lb[NBUCK];
  int tid = threadIdx.x;
  for (int i = tid; i < NBUCK; i += 256) lc[i] = 0;
  __syncthreads();
  int base = blockIdx.x * CH;
  int sj[8], dj[8], rj[8];
#pragma unroll
  for (int j = 0; j < 8; ++j) {
    int i = base + j * 256 + tid;
    if (i < e) {
      sj[j] = src[i]; dj[j] = dst[i];
      rj[j] = atomicAdd(&lc[dj[j] >> SZ_LOG], 1);
    }
  }
  __syncthreads();
  for (int i = tid; i < NBUCK; i += 256) { int c = lc[i]; if (c) lb[i] = atomicAdd(&bcur[i], c); }
  __syncthreads();
#pragma unroll
  for (int j = 0; j < 8; ++j) {
    int i = base + j * 256 + tid;
    if (i < e) ebuck[lb[dj[j] >> SZ_LOG] + rj[j]] = make_int2(sj[j], dj[j]);
  }
}

// D: per-bucket node counts -> off (via LDS scan) + dinv. Kills the global 50k scan.
__global__ __launch_bounds__(256) void k_ncount(const int2* __restrict__ ebuck, const int* __restrict__ boff,
                                                int* __restrict__ off, float* __restrict__ dinv) {
  __shared__ int nc[256];
  __shared__ int sc[256];
  int b = blockIdx.x, tid = threadIdx.x;
  nc[tid] = 0;
  __syncthreads();
  int j0 = boff[b], j1 = boff[b + 1];
  for (int j = j0 + tid; j < j1; j += 256) atomicAdd(&nc[ebuck[j].y & 255], 1);
  __syncthreads();
  int v = nc[tid];
  sc[tid] = v;
  __syncthreads();
  for (int o = 1; o < 256; o <<= 1) {
    int t = (tid >= o) ? sc[tid - o] : 0;
    __syncthreads();
    sc[tid] += t;
    __syncthreads();
  }
  int node = (b << SZ_LOG) + tid;
  if (node < NN) {
    off[node]  = j0 + sc[tid] - v;          // bucket base + exclusive prefix
    dinv[node] = rsqrtf((float)v + 2.0f);   // improved=True self-loop weight 2.0
  }
}

// F: per-bucket fill of final CSR records; LDS cursors, writes land in ~32KB L2-resident window
__global__ __launch_bounds__(256) void k_fill2(const int2* __restrict__ ebuck, const int* __restrict__ boff,
                                               const int* __restrict__ off, const float* __restrict__ dinv,
                                               int2* __restrict__ edges) {
  __shared__ int   lcur[256];
  __shared__ float ldv[256];
  int b = blockIdx.x, tid = threadIdx.x;
  int node = (b << SZ_LOG) + tid;
  lcur[tid] = (node < NN) ? off[node]  : 0;
  ldv[tid]  = (node < NN) ? dinv[node] : 0.f;
  __syncthreads();
  int j0 = boff[b], j1 = boff[b + 1];
  for (int j = j0 + tid; j < j1; j += 256) {
    int2 e = ebuck[j];
    int loc = e.y & 255;
    int pos = atomicAdd(&lcur[loc], 1);
    edges[pos] = make_int2(e.x, __float_as_int(dinv[e.x] * ldv[loc]));
  }
}

// ---------------- weight convert (all four), [K][128] f32 -> tiled bf16 [K/32][128][32] ----
__global__ void k_wconv_all(const float* __restrict__ W1, const float* __restrict__ W2,
                            const float* __restrict__ We, const float* __restrict__ Wf,
                            u16* __restrict__ T1, u16* __restrict__ T2,
                            u16* __restrict__ T3, u16* __restrict__ T4) {
  int i = blockIdx.x * 256 + threadIdx.x;   // 0 .. 81920
  const float* W; u16* o;
  if (i < 32768)      { W = W1; o = T1; }
  else if (i < 49152) { W = W2; o = T2; i -= 32768; }
  else if (i < 65536) { W = We; o = T3; i -= 49152; }
  else                { W = Wf; o = T4; i -= 65536; }
  int k = i >> 7, c = i & 127;
  o[(size_t)((k >> 5) * 128 + c) * 32 + (k & 31)] = f2bf(W[i]);
}

// ---------------- GEMM: [M,K] @ [K,128] -> [M,128], bf16 MFMA, f32 acc ----------------
template<int AFLOAT, int EPI>
__global__ __launch_bounds__(256) void k_gemm(const float* __restrict__ Af, const u16* __restrict__ Ah,
                                              const u16* __restrict__ Wt, const float* __restrict__ bias,
                                              u16* __restrict__ gout, float* __restrict__ fout,
                                              int M, int K) {
  __shared__ u16 Ash[64 * 40];
  __shared__ u16 Bsh[128 * 40];
  const int tid  = threadIdx.x;
  const int lane = tid & 63;
  const int w    = tid >> 6;
  const int row0 = blockIdx.x * 64;
  f32x4 acc[8];
#pragma unroll
  for (int t = 0; t < 8; ++t) acc[t] = (f32x4){0.f, 0.f, 0.f, 0.f};

  const int nk = K >> 5;
  const int r = tid >> 2, kg = tid & 3;
  const int grow_a = row0 + r;
  for (int kb = 0; kb < nk; ++kb) {
    {
      int k0 = kb * 32 + kg * 8;
      alignas(16) u16 v[8];
      if (grow_a < M) {
        if (AFLOAT) {
          const float* p = Af + (size_t)grow_a * K + k0;
          float4 x0 = *(const float4*)(p);
          float4 x1 = *(const float4*)(p + 4);
          v[0] = f2bf(x0.x); v[1] = f2bf(x0.y); v[2] = f2bf(x0.z); v[3] = f2bf(x0.w);
          v[4] = f2bf(x1.x); v[5] = f2bf(x1.y); v[6] = f2bf(x1.z); v[7] = f2bf(x1.w);
        } else {
          *(uint4*)v = *(const uint4*)(Ah + (size_t)grow_a * K + k0);
        }
      } else {
#pragma unroll
        for (int i = 0; i < 8; ++i) v[i] = 0;
      }
      *(uint4*)&Ash[r * 40 + kg * 8] = *(const uint4*)v;
    }
    {
      const u16* wsrc = Wt + (size_t)kb * 4096;
#pragma unroll
      for (int j = 0; j < 2; ++j) {
        int chunk = tid * 2 + j;
        int rowb = chunk >> 2, kk = (chunk & 3) << 3;
        *(uint4*)&Bsh[rowb * 40 + kk] = *(const uint4*)(wsrc + chunk * 8);
      }
    }
    __syncthreads();
    {
      const int rl = lane & 15, kq = lane >> 4;
      short8 af = *(const short8*)&Ash[(w * 16 + rl) * 40 + kq * 8];
#pragma unroll
      for (int t = 0; t < 8; ++t) {
        short8 bf = *(const short8*)&Bsh[(t * 16 + rl) * 40 + kq * 8];
        acc[t] = __builtin_amdgcn_mfma_f32_16x16x32_bf16(
            __builtin_bit_cast(bf16x8, af), __builtin_bit_cast(bf16x8, bf), acc[t], 0, 0, 0);
      }
    }
    __syncthreads();
  }
  const int rl = lane & 15, rq = lane >> 4;
#pragma unroll
  for (int t = 0; t < 8; ++t) {
    int col = t * 16 + rl;
#pragma unroll
    for (int i = 0; i < 4; ++i) {
      int grow = row0 + w * 16 + rq * 4 + i;
      if (grow < M) {
        if (EPI == 0) {
          gout[(size_t)grow * HID + col] = f2bf(acc[t][i]);
        } else {
          float vv = acc[t][i] + bias[col];
          fout[(size_t)grow * HID + col] = 1.0f / (1.0f + __expf(-vv));
        }
      }
    }
  }
}

// ---------------- aggregation: one wave per dst node, 4 edge-groups x 16 lanes ----------------
template<int RELU>
__global__ __launch_bounds__(256) void k_agg(const u16* __restrict__ h, u16* __restrict__ g,
                                             const float* __restrict__ bias, const float* __restrict__ dinv,
                                             const int* __restrict__ off, const int2* __restrict__ edges,
                                             int n) {
  int wave = blockIdx.x * 4 + (threadIdx.x >> 6);
  int lane = threadIdx.x & 63;
  if (wave >= n) return;
  const int d  = wave;
  const int gr = lane >> 4;
  const int t  = lane & 15;
  const int c  = t << 3;
  float a[8];
#pragma unroll
  for (int i = 0; i < 8; ++i) a[i] = 0.f;

  int j  = off[d] + gr;
  const int j1 = off[d + 1];
  for (; j + 4 < j1; j += 8) {
    int2 eA = edges[j], eB = edges[j + 4];
    uint4 vA = *(const uint4*)(h + (size_t)eA.x * HID + c);
    uint4 vB = *(const uint4*)(h + (size_t)eB.x * HID + c);
    float wA = __int_as_float(eA.y), wB = __int_as_float(eB.y);
    a[0] += wA * bflo(vA.x); a[1] += wA * bfhi(vA.x);
    a[2] += wA * bflo(vA.y); a[3] += wA * bfhi(vA.y);
    a[4] += wA * bflo(vA.z); a[5] += wA * bfhi(vA.z);
    a[6] += wA * bflo(vA.w); a[7] += wA * bfhi(vA.w);
    a[0] += wB * bflo(vB.x); a[1] += wB * bfhi(vB.x);
    a[2] += wB * bflo(vB.y); a[3] += wB * bfhi(vB.y);
    a[4] += wB * bflo(vB.z); a[5] += wB * bfhi(vB.z);
    a[6] += wB * bflo(vB.w); a[7] += wB * bfhi(vB.w);
  }
  for (; j < j1; j += 4) {
    int2 eA = edges[j];
    uint4 vA = *(const uint4*)(h + (size_t)eA.x * HID + c);
    float wA = __int_as_float(eA.y);
    a[0] += wA * bflo(vA.x); a[1] += wA * bfhi(vA.x);
    a[2] += wA * bflo(vA.y); a[3] += wA * bfhi(vA.y);
    a[4] += wA * bflo(vA.z); a[5] += wA * bfhi(vA.z);
    a[6] += wA * bflo(vA.w); a[7] += wA * bfhi(vA.w);
  }
#pragma unroll
  for (int i = 0; i < 8; ++i) {
    a[i] += __shfl_xor(a[i], 16);
    a[i] += __shfl_xor(a[i], 32);
  }
  float di = dinv[d];
  float sl = 2.0f * di * di;
  uint4 sv = *(const uint4*)(h + (size_t)d * HID + c);
  const float4 bv0 = *(const float4*)(bias + c);
  const float4 bv1 = *(const float4*)(bias + c + 4);
  a[0] += sl * bflo(sv.x) + bv0.x; a[1] += sl * bfhi(sv.x) + bv0.y;
  a[2] += sl * bflo(sv.y) + bv0.z; a[3] += sl * bfhi(sv.y) + bv0.w;
  a[4] += sl * bflo(sv.z) + bv1.x; a[5] += sl * bfhi(sv.z) + bv1.y;
  a[6] += sl * bflo(sv.w) + bv1.z; a[7] += sl * bfhi(sv.w) + bv1.w;
  if (RELU) {
#pragma unroll
    for (int i = 0; i < 8; ++i) a[i] = fmaxf(a[i], 0.f);
  }
  if (gr == 0) {
    uint4 o;
    o.x = (uint32_t)f2bf(a[0]) | ((uint32_t)f2bf(a[1]) << 16);
    o.y = (uint32_t)f2bf(a[2]) | ((uint32_t)f2bf(a[3]) << 16);
    o.z = (uint32_t)f2bf(a[4]) | ((uint32_t)f2bf(a[5]) << 16);
    o.w = (uint32_t)f2bf(a[6]) | ((uint32_t)f2bf(a[7]) << 16);
    *(uint4*)(g + (size_t)d * HID + c) = o;
  }
}

extern "C" void kernel_launch(void* const* d_in, const int* in_sizes, int n_in,
                              void* d_out, int out_size, void* d_ws, size_t ws_size,
                              hipStream_t stream) {
  const float* x   = (const float*)d_in[0];
  const int*   ei  = (const int*)d_in[1];        // [2, E] int32
  const float* W1  = (const float*)d_in[2];
  const float* b1  = (const float*)d_in[3];
  const float* W2  = (const float*)d_in[4];
  const float* b2  = (const float*)d_in[5];
  const float* We  = (const float*)d_in[6];
  const float* be  = (const float*)d_in[7];
  const float* Wf  = (const float*)d_in[8];
  const float* bfv = (const float*)d_in[9];
  float* out = (float*)d_out;

  const int* src = ei;
  const int* dst = ei + EE;

  char* p = (char*)d_ws;
  auto take = [&](size_t bytes) { char* r = p; p += (bytes + 255) & ~(size_t)255; return r; };
  int*   bcnt  = (int*)take((size_t)NBUCK * 4);
  int*   boff  = (int*)take((size_t)(NBUCK + 1) * 4);
  int*   bcur  = (int*)take((size_t)NBUCK * 4);
  int*   off   = (int*)take((size_t)(NN + 1) * 4);
  float* dinv  = (float*)take((size_t)NN * 4);
  int2*  edges = (int2*)take((size_t)EE * 8);
  u16*   hA    = (u16*)take((size_t)NN * HID * 2);
  u16*   hB    = (u16*)take((size_t)NN * HID * 2);
  u16*   Wt1   = (u16*)take((size_t)FIN * HID * 2);
  u16*   Wt2   = (u16*)take((size_t)HID * HID * 2);
  u16*   Wt3   = (u16*)take((size_t)HID * HID * 2);
  u16*   Wt4   = (u16*)take((size_t)HID * HID * 2);
  // ebuck (6.4MB) aliases hB (12.8MB): ebuck is dead before agg1 writes hB.
  int2*  ebuck = (int2*)hB;

  // bucketed CSR build
  k_zero<<<1, 256, 0, stream>>>(bcnt, NBUCK);
  k_bhist<<<NCBLK, 256, 0, stream>>>(dst, bcnt, EE);
  k_bscan<<<1, 256, 0, stream>>>(bcnt, boff, bcur, off);
  k_bscatter<<<NCBLK, 256, 0, stream>>>(src, dst, bcur, ebuck, EE);
  k_ncount<<<NBUCK, 256, 0, stream>>>(ebuck, boff, off, dinv);
  k_fill2<<<NBUCK, 256, 0, stream>>>(ebuck, boff, off, dinv, edges);

  // weights -> tiled bf16 (single launch)
  k_wconv_all<<<(81920 + 255) / 256, 256, 0, stream>>>(W1, W2, We, Wf, Wt1, Wt2, Wt3, Wt4);

  const int gemm_grid = (NN + 63) / 64;
  const int agg_grid  = (NN + 3) / 4;

  // layer 1: h = x@W1 ; g = relu(Agg(h) + b1)
  k_gemm<1, 0><<<gemm_grid, 256, 0, stream>>>(x, nullptr, Wt1, nullptr, hA, nullptr, NN, FIN);
  k_agg<1><<<agg_grid, 256, 0, stream>>>(hA, hB, b1, dinv, off, edges, NN);
  // layer 2
  k_gemm<0, 0><<<gemm_grid, 256, 0, stream>>>(nullptr, hB, Wt2, nullptr, hA, nullptr, NN, HID);
  k_agg<1><<<agg_grid, 256, 0, stream>>>(hA, hB, b2, dinv, off, edges, NN);
  // layer 3 (no relu)
  k_gemm<0, 0><<<gemm_grid, 256, 0, stream>>>(nullptr, hB, Wt3, nullptr, hA, nullptr, NN, HID);
  k_agg<0><<<agg_grid, 256, 0, stream>>>(hA, hB, be, dinv, off, edges, NN);
  // final dense + sigmoid
  k_gemm<0, 1><<<gemm_grid, 256, 0, stream>>>(nullptr, hB, Wt4, bfv, nullptr, out, NN, HID);
}